// Round 14
// baseline (358.682 us; speedup 1.0000x reference)
//
#include <hip/hip_runtime.h>
#include <hip/hip_bf16.h>

#define B_  8
#define C_  128
#define V_  256
#define T_  128
#define CQK 16
#define CV  64
#define CO1 96
#define VP  (V_ + 2)   // 258
#define TP  (T_ + 2)   // 130

typedef __attribute__((ext_vector_type(8)))  short short8;   // 8 bf16 (one MFMA A/B frag)
typedef __attribute__((ext_vector_type(4)))  short s16x4;    // 4 bf16 (8 B)
typedef __attribute__((ext_vector_type(4)))  float f32x4;    // 16x16 MFMA C/D frag
typedef __attribute__((ext_vector_type(16))) float f32x16;   // 32x32 MFMA C/D frag
typedef __attribute__((ext_vector_type(4)))  unsigned int u32x4;

#define L2E   1.44269504f      // log2(e)
#define EXPB  23.0831204f      // 16 * log2(e): fixed softmax shift (|s| < 16, q,k tanh-bounded)

// Workspace layout (bytes)
#define XP_BYTES   (B_ * VP * TP * C_ * 2)    // x bf16 padded [B][VP][TP][128]
#define AVP_BYTES  (B_ * VP * TP * CV * 2)    // av bf16 padded [B][VP][TP][64] (aliases XP)
#define QKV_OFF    XP_BYTES
#define QKV_BYTES  (B_ * V_ * T_ * CO1 * 2)   // qkv bf16 [B][T][V][96]  (t-major)
#define WQKV_OFF   (QKV_OFF + QKV_BYTES)
#define WQKV_BYTES (9 * CO1 * C_ * 2)         // per-s slice 24576 B, bank-swizzled
#define WAV_OFF    (WQKV_OFF + WQKV_BYTES)
#define WAV_BYTES  (9 * C_ * CV * 2)          // per-s slice 16384 B, bank-swizzled

// async global->LDS, 16B per lane; LDS dest is wave-uniform base + lane*16 (HW rule)
__device__ __forceinline__ void gload_lds16(const void* g, void* l) {
    __builtin_amdgcn_global_load_lds((const __attribute__((address_space(1))) void*)g,
                                     (__attribute__((address_space(3))) void*)l,
                                     16, 0, 0);
}

// ---------------------------------------------------------------------------
// Kernel 0: zero only the halo ring of a padded [B][VP][TP][CH] buffer.
// ---------------------------------------------------------------------------
__global__ __launch_bounds__(256) void zero_halo(__hip_bfloat16* __restrict__ p, int CH) {
    const int b = blockIdx.y;
    const int nrow = 2 * TP * CH;
    const int ncol = (VP - 2) * 2 * CH;
    const __hip_bfloat16 z = __float2bfloat16(0.f);
    for (int e = blockIdx.x * 256 + threadIdx.x; e < nrow + ncol; e += gridDim.x * 256) {
        size_t off;
        if (e < nrow) {
            const int r = e / (TP * CH), k = e % (TP * CH);
            off = (((size_t)b * VP + (size_t)r * (VP - 1)) * TP) * CH + k;
        } else {
            const int e2 = e - nrow;
            const int v = e2 / (2 * CH) + 1, k2 = e2 % (2 * CH);
            const int t = (k2 < CH) ? 0 : (TP - 1);
            const int c = k2 & (CH - 1);
            off = (((size_t)b * VP + v) * TP + t) * CH + c;
        }
        p[off] = z;
    }
}

// ---------------------------------------------------------------------------
// Kernel 1: x [B,C,V,T] fp32 -> XP [B,VP,TP,C] bf16 (interior; halo pre-zeroed)
// ---------------------------------------------------------------------------
__global__ __launch_bounds__(256) void pack_x_kernel(const float* __restrict__ x,
                                                     __hip_bfloat16* __restrict__ xp) {
    __shared__ __hip_bfloat16 tile[T_ * (C_ + 1)];
    const int v = blockIdx.x, b = blockIdx.y, tid = threadIdx.x;

    for (int e = tid; e < C_ * T_; e += 256) {
        const int c = e >> 7, t = e & (T_ - 1);
        tile[t * (C_ + 1) + c] =
            __float2bfloat16(x[(((size_t)b * C_ + c) * V_ + v) * T_ + t]);
    }
    __syncthreads();
    __hip_bfloat16* dst = xp + (((size_t)b * VP + (v + 1)) * TP + 1) * C_;
    for (int e = tid; e < C_ * T_; e += 256) {
        const int t = e >> 7, c = e & (C_ - 1);
        dst[(size_t)t * C_ + c] = tile[t * (C_ + 1) + c];
    }
}

// ---------------------------------------------------------------------------
// Kernel 2: pack weights, PRE-SWIZZLED for LDS bank-friendly ds_read_b128.
//   wqkvp slice s: byte = (co*256 + ci*2) ^ ((co&7)<<4)   (row = 256 B)
//   wavp  slice s: byte = (co*128 + ci*2) ^ ((co&7)<<4)   (row = 128 B)
// ---------------------------------------------------------------------------
__global__ void pack_w_kernel(const float* __restrict__ Wq, const float* __restrict__ Wk,
                              const float* __restrict__ Wv, const float* __restrict__ Wav,
                              __hip_bfloat16* __restrict__ wqkvp,
                              __hip_bfloat16* __restrict__ wavp) {
    const int tid = blockIdx.x * blockDim.x + threadIdx.x;
    const int n1 = 9 * CO1 * C_;
    const int n2 = 9 * C_ * CV;
    for (int e = tid; e < n1 + n2; e += gridDim.x * blockDim.x) {
        if (e < n1) {
            const int s = e / (CO1 * C_), r = e % (CO1 * C_);
            const int co = r / C_, ci = r % C_;
            const int dy = s / 3, dx = s % 3;
            float w;
            if (co < CQK)            w = Wq[(((size_t)co * C_ + ci) * 3 + dy) * 3 + dx];
            else if (co < 2 * CQK)   w = Wk[(((size_t)(co - CQK) * C_ + ci) * 3 + dy) * 3 + dx];
            else                     w = Wv[(((size_t)(co - 2 * CQK) * C_ + ci) * 3 + dy) * 3 + dx];
            const int sw = ((co * 256 + ci * 2) ^ ((co & 7) << 4)) >> 1;
            wqkvp[s * (CO1 * C_) + sw] = __float2bfloat16(w);
        } else {
            const int e2 = e - n1;
            const int s = e2 / (C_ * CV), r = e2 % (C_ * CV);
            const int co = r / CV, ci = r % CV;
            const int dy = s / 3, dx = s % 3;
            const int sw = ((co * 128 + ci * 2) ^ ((co & 7) << 4)) >> 1;
            wavp[s * (C_ * CV) + sw] =
                __float2bfloat16(Wav[(((size_t)co * CV + ci) * 3 + dy) * 3 + dx]);
        }
    }
}

// ---------------------------------------------------------------------------
// Kernel 3: qkv conv, co-split 2x (48 co/block) for occupancy.
// Block = (b, coh, y), 256 thr = 4 waves (t-quarters).  W slice 12.3 KB ->
// dbuf 24.6 KB (6 blocks/CU by LDS); acts loaded SAME-PHASE into regs (no
// cross-barrier liveness -> no spill/sink); plain __syncthreads per phase.
// Epilogue: LDS transpose -> 16-B coalesced t-major stores.
// ---------------------------------------------------------------------------
__global__ __launch_bounds__(256, 4) void conv_qkv_mfma(const __hip_bfloat16* __restrict__ xp,
                                                        const __hip_bfloat16* __restrict__ wqkvp,
                                                        __hip_bfloat16* __restrict__ qkv) {
    __shared__ __align__(16) char wlds[2][12288];
    const int flat = blockIdx.x + (blockIdx.y << 8);
    const int b = flat & 7, coh = (flat >> 3) & 1, y = flat >> 4;
    const int co0 = coh * 48;
    const int tid = threadIdx.x;
    const int wave = tid >> 6, lane = tid & 63;
    const int lane16 = lane & 15, lgrp = lane >> 4;
    const int t0w = wave * 32;

    const char* wbase = (const char*)wqkvp + coh * 12288;

    f32x4 acc[3][2];
    #pragma unroll
    for (int m = 0; m < 3; ++m)
        #pragma unroll
        for (int n = 0; n < 2; ++n) acc[m][n] = (f32x4){0.f, 0.f, 0.f, 0.f};

    // prologue: stage s=0 weight slice (3 gload_lds per wave)
    {
        const char* gsrc = wbase + wave * 3072 + lane * 16;
        char* ldst = &wlds[0][wave * 3072];
        #pragma unroll
        for (int j = 0; j < 3; ++j)
            gload_lds16(gsrc + j * 1024, ldst + j * 1024);
    }
    __syncthreads();

    // swizzled W read offset (local co' = m*16+lane16; co0 mult of 8 -> co&7 = co'&7)
    const int kb6   = (lane16 & 4) << 4;
    const int lbase = lane16 * 256 + ((lgrp * 16) ^ ((lane16 & 3) << 4));

    #pragma unroll
    for (int s = 0; s < 9; ++s) {
        const int cur = s & 1, nxt = cur ^ 1;
        if (s < 8) {   // stage next W slice into the other buffer
            const char* gsrc = wbase + (s + 1) * 24576 + wave * 3072 + lane * 16;
            char* ldst = &wlds[nxt][wave * 3072];
            #pragma unroll
            for (int j = 0; j < 3; ++j)
                gload_lds16(gsrc + j * 1024, ldst + j * 1024);
        }
        const int dy = s / 3, dx = s % 3;
        const __hip_bfloat16* xrow = xp + (((size_t)b * VP + (y + dy)) * TP + dx) * C_;
        // SAME-PHASE act loads (consumed below; short live range, no spill)
        short8 bfr[4][2];
        #pragma unroll
        for (int kk = 0; kk < 4; ++kk)
            #pragma unroll
            for (int nt = 0; nt < 2; ++nt)
                bfr[kk][nt] = *reinterpret_cast<const short8*>(
                    xrow + (size_t)(t0w + nt * 16 + lane16) * C_ + kk * 32 + lgrp * 8);
        const char* wcur = &wlds[cur][0];
        __builtin_amdgcn_s_setprio(1);             // T5
        #pragma unroll
        for (int kk = 0; kk < 4; ++kk) {
            const int koff = lbase + ((kk * 64) ^ kb6);
            #pragma unroll
            for (int m = 0; m < 3; ++m) {
                const short8 afrag = *reinterpret_cast<const short8*>(wcur + koff + m * 4096);
                acc[m][0] = __builtin_amdgcn_mfma_f32_16x16x32_bf16(afrag, bfr[kk][0], acc[m][0], 0, 0, 0);
                acc[m][1] = __builtin_amdgcn_mfma_f32_16x16x32_bf16(afrag, bfr[kk][1], acc[m][1], 0, 0, 0);
            }
        }
        __builtin_amdgcn_s_setprio(0);
        __syncthreads();
    }

    // ---- epilogue: transpose through LDS -> coalesced 16-B qkv stores ----
    // tile [128 t][56 u16] (48 used + 8 pad), 14,336 B, reuses wlds.
    unsigned short* tl = (unsigned short*)&wlds[0][0];
    #pragma unroll
    for (int m = 0; m < 3; ++m) {
        const int col = m * 16 + lgrp * 4;              // local co 0..47
        const int co  = co0 + col;
        #pragma unroll
        for (int nt = 0; nt < 2; ++nt) {
            const int t = t0w + nt * 16 + lane16;
            s16x4 pk4;
            #pragma unroll
            for (int r = 0; r < 4; ++r) {
                float v = acc[m][nt][r];
                if (co + r < 2 * CQK) {
                    v = tanhf(v);
                    if (co + r < CQK) v *= L2E;
                }
                pk4[r] = __builtin_bit_cast(short, __float2bfloat16(v));
            }
            *reinterpret_cast<s16x4*>(&tl[t * 56 + col]) = pk4;
        }
    }
    __syncthreads();
    {
        const int t = tid >> 1, half = tid & 1;         // 2 threads per t-row, 24 co each
        const unsigned short* src = &tl[t * 56 + half * 24];
        __hip_bfloat16* dst = qkv + (((size_t)b * T_ + t) * V_ + y) * CO1 + co0 + half * 24;
        #pragma unroll
        for (int j = 0; j < 3; ++j)
            *reinterpret_cast<short8*>(dst + j * 8) =
                *reinterpret_cast<const short8*>(src + j * 8);
    }
}

// ---------------------------------------------------------------------------
// Kernel 4: MFMA attention.  qkv [B,T,V,96] -> AVP [B,VP,TP,64] bf16 (interior)
// ---------------------------------------------------------------------------
__global__ __launch_bounds__(256) void attn_mfma(const __hip_bfloat16* __restrict__ qkv,
                                                 __hip_bfloat16* __restrict__ avp) {
    __shared__ short qf[8][64][8];
    __shared__ short kf[8][64][8];
    __shared__ short vf[32][64][8];

    const int t   = blockIdx.x & (T_ - 1);
    const int b   = blockIdx.x >> 7;
    const int tid = threadIdx.x;
    const int lane = tid & 63, wid = tid >> 6;
    const int l31 = lane & 31, hi = lane >> 5;

    const __hip_bfloat16* base = qkv + ((size_t)b * T_ + t) * (V_ * CO1);

    #pragma unroll
    for (int pass = 0; pass < 2; ++pass) {
        const int idx = tid + pass * 256;
        const int w = idx >> 1, h = idx & 1;
        const int ls = (w & 31) | (h << 5);
        const short8 qv = *reinterpret_cast<const short8*>(base + (size_t)w * CO1 + h * 8);
        const short8 kv = *reinterpret_cast<const short8*>(base + (size_t)w * CO1 + CQK + h * 8);
        *reinterpret_cast<short8*>(&qf[w >> 5][ls][0]) = qv;
        *reinterpret_cast<short8*>(&kf[w >> 5][ls][0]) = kv;
    }
    {
        const int c = tid & 63, wg = tid >> 6;
        const int ct = c >> 5, c31 = c & 31;
        #pragma unroll
        for (int pass = 0; pass < 8; ++pass) {
            const int w0 = (pass * 4 + wg) * 8;
            short8 vv;
            #pragma unroll
            for (int i = 0; i < 8; ++i)
                vv[i] = *reinterpret_cast<const short*>(base + (size_t)(w0 + i) * CO1 + 2 * CQK + c);
            const int ls = c31 | (((w0 >> 3) & 1) << 5);
            *reinterpret_cast<short8*>(&vf[(w0 >> 4) * 2 + ct][ls][0]) = vv;
        }
    }
    __syncthreads();

    #pragma unroll
    for (int sp = 0; sp < 2; ++sp) {
        const int strip = wid * 2 + sp;
        const short8 bq = *reinterpret_cast<const short8*>(&qf[strip][lane][0]);

        f32x16 o0, o1;
        #pragma unroll
        for (int r = 0; r < 16; ++r) { o0[r] = 0.f; o1[r] = 0.f; }
        float lsum = 0.f;

        for (int wt = 0; wt < 8; ++wt) {
            const short8 ak = *reinterpret_cast<const short8*>(&kf[wt][lane][0]);
            f32x16 st;
            #pragma unroll
            for (int r = 0; r < 16; ++r) st[r] = -EXPB;
            st = __builtin_amdgcn_mfma_f32_32x32x16_bf16(ak, bq, st, 0, 0, 0);

            float p[16];
            #pragma unroll
            for (int r = 0; r < 16; ++r) { p[r] = __builtin_exp2f(st[r]); lsum += p[r]; }

            unsigned pk[8], xpk[8];
            #pragma unroll
            for (int i = 0; i < 8; ++i) {
                const unsigned lo  = __builtin_bit_cast(unsigned short, __float2bfloat16(p[2 * i]));
                const unsigned hiw = __builtin_bit_cast(unsigned short, __float2bfloat16(p[2 * i + 1]));
                pk[i] = lo | (hiw << 16);
            }
            #pragma unroll
            for (int i = 0; i < 8; ++i) xpk[i] = __shfl_xor(pk[i], 32);

            const u32x4 fa0 = hi ? (u32x4){xpk[2], xpk[3], pk[2], pk[3]}
                                 : (u32x4){pk[0], pk[1], xpk[0], xpk[1]};
            const u32x4 fa1 = hi ? (u32x4){xpk[6], xpk[7], pk[6], pk[7]}
                                 : (u32x4){pk[4], pk[5], xpk[4], xpk[5]};
            const short8 a0 = __builtin_bit_cast(short8, fa0);
            const short8 a1 = __builtin_bit_cast(short8, fa1);

            const short8 v00 = *reinterpret_cast<const short8*>(&vf[wt * 4 + 0][lane][0]);
            const short8 v01 = *reinterpret_cast<const short8*>(&vf[wt * 4 + 1][lane][0]);
            const short8 v10 = *reinterpret_cast<const short8*>(&vf[wt * 4 + 2][lane][0]);
            const short8 v11 = *reinterpret_cast<const short8*>(&vf[wt * 4 + 3][lane][0]);

            __builtin_amdgcn_s_setprio(1);
            o0 = __builtin_amdgcn_mfma_f32_32x32x16_bf16(a0, v00, o0, 0, 0, 0);
            o1 = __builtin_amdgcn_mfma_f32_32x32x16_bf16(a0, v01, o1, 0, 0, 0);
            o0 = __builtin_amdgcn_mfma_f32_32x32x16_bf16(a1, v10, o0, 0, 0, 0);
            o1 = __builtin_amdgcn_mfma_f32_32x32x16_bf16(a1, v11, o1, 0, 0, 0);
            __builtin_amdgcn_s_setprio(0);
        }

        lsum += __shfl_xor(lsum, 32);
        const float rl = 1.f / lsum;

        const size_t obase = (((size_t)b * VP) * TP + (t + 1)) * CV;
        #pragma unroll
        for (int r = 0; r < 16; ++r) {
            const int row = (r & 3) + 8 * (r >> 2) + 4 * hi;
            const float rlr = __shfl(rl, row);
            __hip_bfloat16* op = avp + obase + (size_t)(strip * 32 + row + 1) * ((size_t)TP * CV) + l31;
            op[0]  = __float2bfloat16(o0[r] * rlr);
            op[32] = __float2bfloat16(o1[r] * rlr);
        }
    }
}

// ---------------------------------------------------------------------------
// Kernel 5: output conv + residual, co-split 2x (64 co/block).
// Block = (b, coh, y), 4 waves.  W slice 8 KB -> dbuf 16 KB; same-phase act
// loads; plain __syncthreads.  Epilogue: fp32 LDS transpose (2 passes) ->
// float4 coalesced x-load / out-store.
// ---------------------------------------------------------------------------
__global__ __launch_bounds__(256, 4) void conv_out_mfma(const float* __restrict__ x,
                                                        const __hip_bfloat16* __restrict__ avp,
                                                        const __hip_bfloat16* __restrict__ wavp,
                                                        const float* __restrict__ sigma,
                                                        float* __restrict__ out) {
    __shared__ __align__(16) char lds[16896];          // max(2x8192 dbuf, 32x132x4 tile)
    char* wlds0 = lds;
    char* wlds1 = lds + 8192;
    const int flat = blockIdx.x + (blockIdx.y << 8);
    const int b = flat & 7, coh = (flat >> 3) & 1, y = flat >> 4;
    const int co0 = coh * 64;
    const int tid = threadIdx.x;
    const int wave = tid >> 6, lane = tid & 63;
    const int lane16 = lane & 15, lgrp = lane >> 4;
    const int t0w = wave * 32;
    const float sig = sigma[0];

    const char* wbase = (const char*)wavp + coh * 8192;

    f32x4 acc[4][2];
    #pragma unroll
    for (int m = 0; m < 4; ++m)
        #pragma unroll
        for (int n = 0; n < 2; ++n) acc[m][n] = (f32x4){0.f, 0.f, 0.f, 0.f};

    {
        const char* gsrc = wbase + wave * 2048 + lane * 16;
        char* ldst = wlds0 + wave * 2048;
        #pragma unroll
        for (int j = 0; j < 2; ++j)
            gload_lds16(gsrc + j * 1024, ldst + j * 1024);
    }
    __syncthreads();

    const int kb6   = (lane16 & 4) << 4;
    const int lbase = lane16 * 128 + ((lgrp * 16) ^ ((lane16 & 3) << 4));

    #pragma unroll
    for (int s = 0; s < 9; ++s) {
        const char* wcur = (s & 1) ? wlds1 : wlds0;
        char*       wnxt = (s & 1) ? wlds0 : wlds1;
        if (s < 8) {
            const char* gsrc = wbase + (s + 1) * 16384 + wave * 2048 + lane * 16;
            char* ldst = wnxt + wave * 2048;
            #pragma unroll
            for (int j = 0; j < 2; ++j)
                gload_lds16(gsrc + j * 1024, ldst + j * 1024);
        }
        const int dy = s / 3, dx = s % 3;
        const __hip_bfloat16* arow = avp + (((size_t)b * VP + (y + dy)) * TP + dx) * CV;
        short8 bfr[2][2];
        #pragma unroll
        for (int kk = 0; kk < 2; ++kk)
            #pragma unroll
            for (int nt = 0; nt < 2; ++nt)
                bfr[kk][nt] = *reinterpret_cast<const short8*>(
                    arow + (size_t)(t0w + nt * 16 + lane16) * CV + kk * 32 + lgrp * 8);
        __builtin_amdgcn_s_setprio(1);             // T5
        #pragma unroll
        for (int kk = 0; kk < 2; ++kk) {
            const int koff = lbase + ((kk * 64) ^ kb6);
            #pragma unroll
            for (int m = 0; m < 4; ++m) {
                const short8 afrag = *reinterpret_cast<const short8*>(wcur + koff + m * 2048);
                acc[m][0] = __builtin_amdgcn_mfma_f32_16x16x32_bf16(afrag, bfr[kk][0], acc[m][0], 0, 0, 0);
                acc[m][1] = __builtin_amdgcn_mfma_f32_16x16x32_bf16(afrag, bfr[kk][1], acc[m][1], 0, 0, 0);
            }
        }
        __builtin_amdgcn_s_setprio(0);
        __syncthreads();
    }

    // ---- epilogue: fp32 transpose, 2 passes of 32 co -> float4 stores ----
    float* tl = (float*)lds;                           // [32 co][132 f32]
    const int co_q = tid >> 3;                          // 0..31
    const int tt0  = (tid & 7) * 16;
    #pragma unroll
    for (int p = 0; p < 2; ++p) {
        #pragma unroll
        for (int mm = 0; mm < 2; ++mm) {                // m = p*2+mm
            const int m  = p * 2 + mm;
            const int cl = mm * 16 + lgrp * 4;          // row within pass tile
            #pragma unroll
            for (int nt = 0; nt < 2; ++nt) {
                const int t = t0w + nt * 16 + lane16;
                #pragma unroll
                for (int r = 0; r < 4; ++r)
                    tl[(cl + r) * 132 + t] = acc[m][nt][r];
            }
        }
        __syncthreads();
        const int co = co0 + p * 32 + co_q;
        const float* xs = x   + (((size_t)b * C_ + co) * V_ + y) * T_ + tt0;
        float*       os = out + (((size_t)b * C_ + co) * V_ + y) * T_ + tt0;
        #pragma unroll
        for (int j = 0; j < 4; ++j) {
            const f32x4 xv = *reinterpret_cast<const f32x4*>(xs + j * 4);
            const f32x4 cv = *reinterpret_cast<const f32x4*>(&tl[co_q * 132 + tt0 + j * 4]);
            f32x4 ov;
            ov[0] = xv[0] + sig * cv[0];
            ov[1] = xv[1] + sig * cv[1];
            ov[2] = xv[2] + sig * cv[2];
            ov[3] = xv[3] + sig * cv[3];
            *reinterpret_cast<f32x4*>(os + j * 4) = ov;
        }
        if (p == 0) __syncthreads();
    }
}

// ---------------------------------------------------------------------------
extern "C" void kernel_launch(void* const* d_in, const int* in_sizes, int n_in,
                              void* d_out, int out_size, void* d_ws, size_t ws_size,
                              hipStream_t stream) {
    const float* x     = (const float*)d_in[0];
    const float* Wq    = (const float*)d_in[1];
    const float* Wk    = (const float*)d_in[2];
    const float* Wv    = (const float*)d_in[3];
    const float* Wav   = (const float*)d_in[4];
    const float* sigma = (const float*)d_in[5];
    float* out = (float*)d_out;

    char* wsp = (char*)d_ws;
    __hip_bfloat16* xp    = (__hip_bfloat16*)wsp;               // padded x (bf16)
    __hip_bfloat16* avp   = (__hip_bfloat16*)wsp;               // padded av (aliases xp)
    __hip_bfloat16* qkv   = (__hip_bfloat16*)(wsp + QKV_OFF);
    __hip_bfloat16* wqkvp = (__hip_bfloat16*)(wsp + WQKV_OFF);
    __hip_bfloat16* wavp  = (__hip_bfloat16*)(wsp + WAV_OFF);

    // 0. zero XP halo only (interior fully written by pack_x)
    zero_halo<<<dim3(64, B_), dim3(256), 0, stream>>>(xp, C_);
    // 1. x -> padded channels-last bf16
    pack_x_kernel<<<dim3(V_, B_), dim3(256), 0, stream>>>(x, xp);
    // 2. pack weights (pre-swizzled rows)
    pack_w_kernel<<<dim3(32), dim3(256), 0, stream>>>(Wq, Wk, Wv, Wav, wqkvp, wavp);
    // 3. qkv conv (co-split x2, same-phase acts, 24.6 KB LDS -> high occupancy)
    conv_qkv_mfma<<<dim3(256, 16), dim3(256), 0, stream>>>(xp, wqkvp, qkv);
    // 4. zero AVP halo (aliases XP; conv_qkv done reading xp by stream order)
    zero_halo<<<dim3(64, B_), dim3(256), 0, stream>>>(avp, CV);
    // 5. attention (MFMA, swapped-QK, fixed shift, setprio)
    attn_mfma<<<dim3(B_ * T_), dim3(256), 0, stream>>>(qkv, avp);
    // 6. output conv (co-split x2, 16 KB dbuf) + residual
    conv_out_mfma<<<dim3(256, 16), dim3(256), 0, stream>>>(x, avp, wavp, sigma, out);
}

// Round 15
// 265.729 us; speedup vs baseline: 1.3498x; 1.3498x over previous
//
#include <hip/hip_runtime.h>
#include <hip/hip_bf16.h>

#define B_  8
#define C_  128
#define V_  256
#define T_  128
#define CQK 16
#define CV  64
#define CO1 96
#define VP  (V_ + 2)   // 258
#define TP  (T_ + 2)   // 130

typedef __attribute__((ext_vector_type(8)))  short short8;   // 8 bf16 (one MFMA A/B frag)
typedef __attribute__((ext_vector_type(4)))  short s16x4;    // 4 bf16 (8 B)
typedef __attribute__((ext_vector_type(4)))  float f32x4;    // 16x16 MFMA C/D frag
typedef __attribute__((ext_vector_type(16))) float f32x16;   // 32x32 MFMA C/D frag
typedef __attribute__((ext_vector_type(4)))  unsigned int u32x4;

#define L2E   1.44269504f      // log2(e)
#define EXPB  23.0831204f      // 16 * log2(e): fixed softmax shift (|s| < 16, q,k tanh-bounded)

// Workspace layout (bytes)
#define XP_BYTES   (B_ * VP * TP * C_ * 2)    // x bf16 padded [B][VP][TP][128]
#define AVP_BYTES  (B_ * VP * TP * CV * 2)    // av bf16 padded [B][VP][TP][64] (aliases XP)
#define QKV_OFF    XP_BYTES
#define QKV_BYTES  (B_ * V_ * T_ * CO1 * 2)   // qkv bf16 [B][T][V][96]  (t-major)
#define WQKV_OFF   (QKV_OFF + QKV_BYTES)
#define WQKV_BYTES (9 * CO1 * C_ * 2)         // per-s slice 24576 B, bank-swizzled
#define WAV_OFF    (WQKV_OFF + WQKV_BYTES)
#define WAV_BYTES  (9 * C_ * CV * 2)          // per-s slice 16384 B, bank-swizzled

// async global->LDS, 16B per lane; LDS dest is wave-uniform base + lane*16 (HW rule)
__device__ __forceinline__ void gload_lds16(const void* g, void* l) {
    __builtin_amdgcn_global_load_lds((const __attribute__((address_space(1))) void*)g,
                                     (__attribute__((address_space(3))) void*)l,
                                     16, 0, 0);
}

// Counted-vmcnt phase barrier (T4): the N newest vmem ops (activation prefetch)
// may stay in flight across the barrier; everything older (weight staging) must
// be complete.  Never drains vmcnt to 0 inside the loop.
#define PHASE_BARRIER(N)                                            \
    do {                                                            \
        __builtin_amdgcn_sched_barrier(0);                          \
        asm volatile("s_waitcnt vmcnt(" #N ")" ::: "memory");       \
        __builtin_amdgcn_s_barrier();                               \
        __builtin_amdgcn_sched_barrier(0);                          \
    } while (0)

// ---------------------------------------------------------------------------
// Kernel 1: x [B,C,V,T] fp32 -> XP [B,VP,TP,C] bf16, WITH fused halo zeroing:
//  - every block zeros its padded row's t=0 / t=TP-1 cells
//  - v==0 block zeros padded row 0; v==V_-1 block zeros padded row VP-1
// ---------------------------------------------------------------------------
__global__ __launch_bounds__(256) void pack_x_kernel(const float* __restrict__ x,
                                                     __hip_bfloat16* __restrict__ xp) {
    __shared__ __hip_bfloat16 tile[T_ * (C_ + 1)];
    const int v = blockIdx.x, b = blockIdx.y, tid = threadIdx.x;
    const __hip_bfloat16 z = __float2bfloat16(0.f);

    __hip_bfloat16* rowp = xp + (((size_t)b * VP + (v + 1)) * TP) * C_;
    // fused halo: this row's t=0 and t=TP-1 cells (2*C_ = 256 elements)
    {
        const int c = tid & (C_ - 1);
        rowp[((tid < C_) ? 0 : (TP - 1)) * C_ + c] = z;
    }
    if (v == 0) {                 // padded v-row 0, full
        __hip_bfloat16* r0 = xp + (((size_t)b * VP + 0) * TP) * C_;
        for (int e = tid; e < TP * C_; e += 256) r0[e] = z;
    } else if (v == V_ - 1) {     // padded v-row VP-1, full
        __hip_bfloat16* r1 = xp + (((size_t)b * VP + (VP - 1)) * TP) * C_;
        for (int e = tid; e < TP * C_; e += 256) r1[e] = z;
    }

    for (int e = tid; e < C_ * T_; e += 256) {
        const int c = e >> 7, t = e & (T_ - 1);
        tile[t * (C_ + 1) + c] =
            __float2bfloat16(x[(((size_t)b * C_ + c) * V_ + v) * T_ + t]);
    }
    __syncthreads();
    __hip_bfloat16* dst = rowp + C_;           // (v+1, t=1)
    for (int e = tid; e < C_ * T_; e += 256) {
        const int t = e >> 7, c = e & (C_ - 1);
        dst[(size_t)t * C_ + c] = tile[t * (C_ + 1) + c];
    }
}

// ---------------------------------------------------------------------------
// Kernel 2: pack weights, PRE-SWIZZLED for LDS bank-friendly ds_read_b128.
//   wqkvp slice s: byte = (co*256 + ci*2) ^ ((co&7)<<4)   (row = 256 B)
//   wavp  slice s: byte = (co*128 + ci*2) ^ ((co&7)<<4)   (row = 128 B)
// ---------------------------------------------------------------------------
__global__ void pack_w_kernel(const float* __restrict__ Wq, const float* __restrict__ Wk,
                              const float* __restrict__ Wv, const float* __restrict__ Wav,
                              __hip_bfloat16* __restrict__ wqkvp,
                              __hip_bfloat16* __restrict__ wavp) {
    const int tid = blockIdx.x * blockDim.x + threadIdx.x;
    const int n1 = 9 * CO1 * C_;
    const int n2 = 9 * C_ * CV;
    for (int e = tid; e < n1 + n2; e += gridDim.x * blockDim.x) {
        if (e < n1) {
            const int s = e / (CO1 * C_), r = e % (CO1 * C_);
            const int co = r / C_, ci = r % C_;
            const int dy = s / 3, dx = s % 3;
            float w;
            if (co < CQK)            w = Wq[(((size_t)co * C_ + ci) * 3 + dy) * 3 + dx];
            else if (co < 2 * CQK)   w = Wk[(((size_t)(co - CQK) * C_ + ci) * 3 + dy) * 3 + dx];
            else                     w = Wv[(((size_t)(co - 2 * CQK) * C_ + ci) * 3 + dy) * 3 + dx];
            const int sw = ((co * 256 + ci * 2) ^ ((co & 7) << 4)) >> 1;
            wqkvp[s * (CO1 * C_) + sw] = __float2bfloat16(w);
        } else {
            const int e2 = e - n1;
            const int s = e2 / (C_ * CV), r = e2 % (C_ * CV);
            const int co = r / CV, ci = r % CV;
            const int dy = s / 3, dx = s % 3;
            const int sw = ((co * 128 + ci * 2) ^ ((co & 7) << 4)) >> 1;
            wavp[s * (C_ * CV) + sw] =
                __float2bfloat16(Wav[(((size_t)co * CV + ci) * 3 + dy) * 3 + dx]);
        }
    }
}

// ---------------------------------------------------------------------------
// Kernel 3: qkv conv via MFMA (R13-verified).  XP -> qkv [B,T,V,96].
// Counted-vmcnt phases, setprio around MFMA, transposed coalesced epilogue.
// ---------------------------------------------------------------------------
__global__ __launch_bounds__(256, 3) void conv_qkv_mfma(const __hip_bfloat16* __restrict__ xp,
                                                        const __hip_bfloat16* __restrict__ wqkvp,
                                                        __hip_bfloat16* __restrict__ qkv) {
    __shared__ __align__(16) char wlds[2][24576];
    const int flat = blockIdx.x + (blockIdx.y << 8);
    const int y = flat >> 3, b = flat & 7;
    const int tid = threadIdx.x;
    const int wave = tid >> 6, lane = tid & 63;
    const int lane16 = lane & 15, lgrp = lane >> 4;
    const int t0w = wave * 32;

    const char* wbase = (const char*)wqkvp;

    f32x4 acc[6][2];
    #pragma unroll
    for (int m = 0; m < 6; ++m)
        #pragma unroll
        for (int n = 0; n < 2; ++n) acc[m][n] = (f32x4){0.f, 0.f, 0.f, 0.f};

    short8 bfr[2][4][2];
    // prologue: stage s=0 weights, then s=0 activation frags
    {
        const char* gsrc = wbase + wave * 6144 + lane * 16;
        char* ldst = &wlds[0][wave * 6144];
        #pragma unroll
        for (int j = 0; j < 6; ++j)
            gload_lds16(gsrc + j * 1024, ldst + j * 1024);
        __builtin_amdgcn_sched_barrier(0);
        const __hip_bfloat16* xrow = xp + (((size_t)b * VP + y) * TP + 0) * C_;  // dy=0,dx=0
        #pragma unroll
        for (int kk = 0; kk < 4; ++kk)
            #pragma unroll
            for (int nt = 0; nt < 2; ++nt)
                bfr[0][kk][nt] = *reinterpret_cast<const short8*>(
                    xrow + (size_t)(t0w + nt * 16 + lane16) * C_ + kk * 32 + lgrp * 8);
    }
    PHASE_BARRIER(8);   // weights for s=0 landed; the 8 act loads wait at first use

    // swizzled read offset: (co*256 + kk*64 + lgrp*16) ^ ((co&7)<<4), co = m*16+lane16
    const int kb6   = (lane16 & 4) << 4;
    const int lbase = lane16 * 256 + ((lgrp * 16) ^ ((lane16 & 3) << 4));

    #pragma unroll
    for (int s = 0; s < 9; ++s) {
        const int cur = s & 1, nxt = cur ^ 1;
        if (s < 8) {   // prefetch weights (LDS) then activations (regs) for s+1
            const char* gsrc = wbase + (s + 1) * 24576 + wave * 6144 + lane * 16;
            char* ldst = &wlds[nxt][wave * 6144];
            #pragma unroll
            for (int j = 0; j < 6; ++j)
                gload_lds16(gsrc + j * 1024, ldst + j * 1024);
            __builtin_amdgcn_sched_barrier(0);     // pin: weights issued before acts
            const int dy = (s + 1) / 3, dx = (s + 1) % 3;
            const __hip_bfloat16* xrow = xp + (((size_t)b * VP + (y + dy)) * TP + dx) * C_;
            #pragma unroll
            for (int kk = 0; kk < 4; ++kk)
                #pragma unroll
                for (int nt = 0; nt < 2; ++nt)
                    bfr[nxt][kk][nt] = *reinterpret_cast<const short8*>(
                        xrow + (size_t)(t0w + nt * 16 + lane16) * C_ + kk * 32 + lgrp * 8);
            __builtin_amdgcn_sched_barrier(0);     // pin prefetch issue into phase s
        }
        const char* wcur = &wlds[cur][0];
        __builtin_amdgcn_s_setprio(1);             // T5: favor MFMA-entering waves
        #pragma unroll
        for (int kk = 0; kk < 4; ++kk) {
            const int koff = lbase + ((kk * 64) ^ kb6);
            #pragma unroll
            for (int m = 0; m < 6; ++m) {
                const short8 afrag = *reinterpret_cast<const short8*>(wcur + koff + m * 4096);
                acc[m][0] = __builtin_amdgcn_mfma_f32_16x16x32_bf16(afrag, bfr[cur][kk][0], acc[m][0], 0, 0, 0);
                acc[m][1] = __builtin_amdgcn_mfma_f32_16x16x32_bf16(afrag, bfr[cur][kk][1], acc[m][1], 0, 0, 0);
            }
        }
        __builtin_amdgcn_s_setprio(0);
        if (s < 8) PHASE_BARRIER(8);   // weight stage done; 8 act loads stay in flight
    }
    __syncthreads();   // full drain before reusing wlds as transpose scratch

    // ---- epilogue: transpose through LDS -> coalesced 16-B qkv stores ----
    unsigned short* tl = (unsigned short*)&wlds[0][0];
    #pragma unroll
    for (int m = 0; m < 6; ++m) {
        const int co = m * 16 + lgrp * 4;
        #pragma unroll
        for (int nt = 0; nt < 2; ++nt) {
            const int t = t0w + nt * 16 + lane16;
            s16x4 pk4;
            #pragma unroll
            for (int r = 0; r < 4; ++r) {
                float v = acc[m][nt][r];
                if (co + r < 2 * CQK) {
                    v = tanhf(v);
                    if (co + r < CQK) v *= L2E;
                }
                pk4[r] = __builtin_bit_cast(short, __float2bfloat16(v));
            }
            *reinterpret_cast<s16x4*>(&tl[t * 104 + co]) = pk4;
        }
    }
    __syncthreads();
    {
        const int t = tid >> 1, half = tid & 1;
        const unsigned short* src = &tl[t * 104 + half * 48];
        __hip_bfloat16* dst = qkv + (((size_t)b * T_ + t) * V_ + y) * CO1 + half * 48;
        #pragma unroll
        for (int j = 0; j < 6; ++j)
            *reinterpret_cast<short8*>(dst + j * 8) =
                *reinterpret_cast<const short8*>(src + j * 8);
    }
}

// ---------------------------------------------------------------------------
// Kernel 4: MFMA attention.  qkv [B,T,V,96] -> AVP [B,VP,TP,64] bf16,
// WITH fused AVP halo zeroing:
//  - every block zeros its t-column (t+1) in padded v-rows 0 and VP-1
//  - t==0 block zeros the t=0 column for all padded v; t==T_-1 zeros t=TP-1
// ---------------------------------------------------------------------------
__global__ __launch_bounds__(256) void attn_mfma(const __hip_bfloat16* __restrict__ qkv,
                                                 __hip_bfloat16* __restrict__ avp) {
    __shared__ short qf[8][64][8];
    __shared__ short kf[8][64][8];
    __shared__ short vf[32][64][8];

    const int t   = blockIdx.x & (T_ - 1);
    const int b   = blockIdx.x >> 7;
    const int tid = threadIdx.x;
    const int lane = tid & 63, wid = tid >> 6;
    const int l31 = lane & 31, hi = lane >> 5;

    // ---- fused AVP halo zeroing (disjoint from interior writes) ----
    {
        const __hip_bfloat16 z = __float2bfloat16(0.f);
        __hip_bfloat16* bb = avp + ((size_t)b * VP) * TP * CV;
        // this block's t-column (t+1) in v-rows 0 and VP-1  (2*CV = 128 els)
        if (tid < 2 * CV) {
            const int vrow = (tid < CV) ? 0 : (VP - 1);
            bb[((size_t)vrow * TP + (t + 1)) * CV + (tid & (CV - 1))] = z;
        }
        if (t == 0) {            // t=0 column, all padded v (VP*CV = 16512 els)
            for (int e = tid; e < VP * CV; e += 256)
                bb[((size_t)(e >> 6) * TP + 0) * CV + (e & (CV - 1))] = z;
        } else if (t == T_ - 1) { // t=TP-1 column, all padded v
            for (int e = tid; e < VP * CV; e += 256)
                bb[((size_t)(e >> 6) * TP + (TP - 1)) * CV + (e & (CV - 1))] = z;
        }
    }

    const __hip_bfloat16* base = qkv + ((size_t)b * T_ + t) * (V_ * CO1);

    #pragma unroll
    for (int pass = 0; pass < 2; ++pass) {
        const int idx = tid + pass * 256;
        const int w = idx >> 1, h = idx & 1;
        const int ls = (w & 31) | (h << 5);
        const short8 qv = *reinterpret_cast<const short8*>(base + (size_t)w * CO1 + h * 8);
        const short8 kv = *reinterpret_cast<const short8*>(base + (size_t)w * CO1 + CQK + h * 8);
        *reinterpret_cast<short8*>(&qf[w >> 5][ls][0]) = qv;
        *reinterpret_cast<short8*>(&kf[w >> 5][ls][0]) = kv;
    }
    {
        const int c = tid & 63, wg = tid >> 6;
        const int ct = c >> 5, c31 = c & 31;
        #pragma unroll
        for (int pass = 0; pass < 8; ++pass) {
            const int w0 = (pass * 4 + wg) * 8;
            short8 vv;
            #pragma unroll
            for (int i = 0; i < 8; ++i)
                vv[i] = *reinterpret_cast<const short*>(base + (size_t)(w0 + i) * CO1 + 2 * CQK + c);
            const int ls = c31 | (((w0 >> 3) & 1) << 5);
            *reinterpret_cast<short8*>(&vf[(w0 >> 4) * 2 + ct][ls][0]) = vv;
        }
    }
    __syncthreads();

    #pragma unroll
    for (int sp = 0; sp < 2; ++sp) {
        const int strip = wid * 2 + sp;
        const short8 bq = *reinterpret_cast<const short8*>(&qf[strip][lane][0]);

        f32x16 o0, o1;
        #pragma unroll
        for (int r = 0; r < 16; ++r) { o0[r] = 0.f; o1[r] = 0.f; }
        float lsum = 0.f;

        for (int wt = 0; wt < 8; ++wt) {
            const short8 ak = *reinterpret_cast<const short8*>(&kf[wt][lane][0]);
            f32x16 st;
            #pragma unroll
            for (int r = 0; r < 16; ++r) st[r] = -EXPB;
            st = __builtin_amdgcn_mfma_f32_32x32x16_bf16(ak, bq, st, 0, 0, 0);

            float p[16];
            #pragma unroll
            for (int r = 0; r < 16; ++r) { p[r] = __builtin_exp2f(st[r]); lsum += p[r]; }

            unsigned pk[8], xpk[8];
            #pragma unroll
            for (int i = 0; i < 8; ++i) {
                const unsigned lo  = __builtin_bit_cast(unsigned short, __float2bfloat16(p[2 * i]));
                const unsigned hiw = __builtin_bit_cast(unsigned short, __float2bfloat16(p[2 * i + 1]));
                pk[i] = lo | (hiw << 16);
            }
            #pragma unroll
            for (int i = 0; i < 8; ++i) xpk[i] = __shfl_xor(pk[i], 32);

            const u32x4 fa0 = hi ? (u32x4){xpk[2], xpk[3], pk[2], pk[3]}
                                 : (u32x4){pk[0], pk[1], xpk[0], xpk[1]};
            const u32x4 fa1 = hi ? (u32x4){xpk[6], xpk[7], pk[6], pk[7]}
                                 : (u32x4){pk[4], pk[5], xpk[4], xpk[5]};
            const short8 a0 = __builtin_bit_cast(short8, fa0);
            const short8 a1 = __builtin_bit_cast(short8, fa1);

            const short8 v00 = *reinterpret_cast<const short8*>(&vf[wt * 4 + 0][lane][0]);
            const short8 v01 = *reinterpret_cast<const short8*>(&vf[wt * 4 + 1][lane][0]);
            const short8 v10 = *reinterpret_cast<const short8*>(&vf[wt * 4 + 2][lane][0]);
            const short8 v11 = *reinterpret_cast<const short8*>(&vf[wt * 4 + 3][lane][0]);

            __builtin_amdgcn_s_setprio(1);
            o0 = __builtin_amdgcn_mfma_f32_32x32x16_bf16(a0, v00, o0, 0, 0, 0);
            o1 = __builtin_amdgcn_mfma_f32_32x32x16_bf16(a0, v01, o1, 0, 0, 0);
            o0 = __builtin_amdgcn_mfma_f32_32x32x16_bf16(a1, v10, o0, 0, 0, 0);
            o1 = __builtin_amdgcn_mfma_f32_32x32x16_bf16(a1, v11, o1, 0, 0, 0);
            __builtin_amdgcn_s_setprio(0);
        }

        lsum += __shfl_xor(lsum, 32);
        const float rl = 1.f / lsum;

        const size_t obase = (((size_t)b * VP) * TP + (t + 1)) * CV;
        #pragma unroll
        for (int r = 0; r < 16; ++r) {
            const int row = (r & 3) + 8 * (r >> 2) + 4 * hi;
            const float rlr = __shfl(rl, row);
            __hip_bfloat16* op = avp + obase + (size_t)(strip * 32 + row + 1) * ((size_t)TP * CV) + l31;
            op[0]  = __float2bfloat16(o0[r] * rlr);
            op[32] = __float2bfloat16(o1[r] * rlr);
        }
    }
}

// ---------------------------------------------------------------------------
// Kernel 5: output conv + residual (R13-verified: counted-vmcnt + setprio +
// transposed coalesced epilogue).
// ---------------------------------------------------------------------------
__global__ __launch_bounds__(256, 2) void conv_out_mfma(const float* __restrict__ x,
                                                        const __hip_bfloat16* __restrict__ avp,
                                                        const __hip_bfloat16* __restrict__ wavp,
                                                        const float* __restrict__ sigma,
                                                        float* __restrict__ out) {
    __shared__ __align__(16) char wlds[2][16384];
    const int flat = blockIdx.x + (blockIdx.y << 8);
    const int y = flat >> 3, b = flat & 7;
    const int tid = threadIdx.x;
    const int wave = tid >> 6, lane = tid & 63;
    const int lane16 = lane & 15, lgrp = lane >> 4;
    const int t0w = wave * 32;
    const float sig = sigma[0];

    const char* wbase = (const char*)wavp;

    f32x4 acc[8][2];
    #pragma unroll
    for (int m = 0; m < 8; ++m)
        #pragma unroll
        for (int n = 0; n < 2; ++n) acc[m][n] = (f32x4){0.f, 0.f, 0.f, 0.f};

    short8 bfr[2][2][2];
    {
        const char* gsrc = wbase + wave * 4096 + lane * 16;
        char* ldst = &wlds[0][wave * 4096];
        #pragma unroll
        for (int j = 0; j < 4; ++j)
            gload_lds16(gsrc + j * 1024, ldst + j * 1024);
        __builtin_amdgcn_sched_barrier(0);
        const __hip_bfloat16* arow = avp + (((size_t)b * VP + y) * TP + 0) * CV;   // dy=0,dx=0
        #pragma unroll
        for (int kk = 0; kk < 2; ++kk)
            #pragma unroll
            for (int nt = 0; nt < 2; ++nt)
                bfr[0][kk][nt] = *reinterpret_cast<const short8*>(
                    arow + (size_t)(t0w + nt * 16 + lane16) * CV + kk * 32 + lgrp * 8);
    }
    PHASE_BARRIER(4);

    const int kb6   = (lane16 & 4) << 4;
    const int lbase = lane16 * 128 + ((lgrp * 16) ^ ((lane16 & 3) << 4));

    #pragma unroll
    for (int s = 0; s < 9; ++s) {
        const int cur = s & 1, nxt = cur ^ 1;
        if (s < 8) {
            const char* gsrc = wbase + (s + 1) * 16384 + wave * 4096 + lane * 16;
            char* ldst = &wlds[nxt][wave * 4096];
            #pragma unroll
            for (int j = 0; j < 4; ++j)
                gload_lds16(gsrc + j * 1024, ldst + j * 1024);
            __builtin_amdgcn_sched_barrier(0);     // pin: weights issued before acts
            const int dy = (s + 1) / 3, dx = (s + 1) % 3;
            const __hip_bfloat16* arow = avp + (((size_t)b * VP + (y + dy)) * TP + dx) * CV;
            #pragma unroll
            for (int kk = 0; kk < 2; ++kk)
                #pragma unroll
                for (int nt = 0; nt < 2; ++nt)
                    bfr[nxt][kk][nt] = *reinterpret_cast<const short8*>(
                        arow + (size_t)(t0w + nt * 16 + lane16) * CV + kk * 32 + lgrp * 8);
            __builtin_amdgcn_sched_barrier(0);     // pin prefetch issue into phase s
        }
        const char* wcur = &wlds[cur][0];
        __builtin_amdgcn_s_setprio(1);             // T5
        #pragma unroll
        for (int kk = 0; kk < 2; ++kk) {
            const int koff = lbase + ((kk * 64) ^ kb6);
            #pragma unroll
            for (int m = 0; m < 8; ++m) {
                const short8 afrag = *reinterpret_cast<const short8*>(wcur + koff + m * 2048);
                acc[m][0] = __builtin_amdgcn_mfma_f32_16x16x32_bf16(afrag, bfr[cur][kk][0], acc[m][0], 0, 0, 0);
                acc[m][1] = __builtin_amdgcn_mfma_f32_16x16x32_bf16(afrag, bfr[cur][kk][1], acc[m][1], 0, 0, 0);
            }
        }
        __builtin_amdgcn_s_setprio(0);
        if (s < 8) PHASE_BARRIER(4);
    }
    __syncthreads();   // full drain before reusing wlds as transpose scratch

    // ---- epilogue: LDS transpose -> float4 coalesced x-load / out-store ----
    float* tl = (float*)&wlds[0][0];                 // 32 KB scratch (W reads all done)
    const int co_q = tid >> 3;                        // 0..31: row this thread reads back
    const int tt0  = (tid & 7) * 16;                  // t base (8 threads span the row)
    #pragma unroll
    for (int p = 0; p < 4; ++p) {
        #pragma unroll
        for (int mm = 0; mm < 2; ++mm) {              // m = p*2+mm
            const int m  = p * 2 + mm;
            const int cl = mm * 16 + lgrp * 4;        // row within quarter
            #pragma unroll
            for (int nt = 0; nt < 2; ++nt) {
                const int t = t0w + nt * 16 + lane16;
                #pragma unroll
                for (int r = 0; r < 4; ++r)
                    tl[(cl + r) * 132 + t] = acc[m][nt][r];
            }
        }
        __syncthreads();
        const int co = p * 32 + co_q;
        const float* xs = x   + (((size_t)b * C_ + co) * V_ + y) * T_ + tt0;
        float*       os = out + (((size_t)b * C_ + co) * V_ + y) * T_ + tt0;
        #pragma unroll
        for (int j = 0; j < 4; ++j) {
            const f32x4 xv = *reinterpret_cast<const f32x4*>(xs + j * 4);
            const f32x4 cv = *reinterpret_cast<const f32x4*>(&tl[co_q * 132 + tt0 + j * 4]);
            f32x4 ov;
            ov[0] = xv[0] + sig * cv[0];
            ov[1] = xv[1] + sig * cv[1];
            ov[2] = xv[2] + sig * cv[2];
            ov[3] = xv[3] + sig * cv[3];
            *reinterpret_cast<f32x4*>(os + j * 4) = ov;
        }
        if (p < 3) __syncthreads();                   // protect next write pass
    }
}

// ---------------------------------------------------------------------------
extern "C" void kernel_launch(void* const* d_in, const int* in_sizes, int n_in,
                              void* d_out, int out_size, void* d_ws, size_t ws_size,
                              hipStream_t stream) {
    const float* x     = (const float*)d_in[0];
    const float* Wq    = (const float*)d_in[1];
    const float* Wk    = (const float*)d_in[2];
    const float* Wv    = (const float*)d_in[3];
    const float* Wav   = (const float*)d_in[4];
    const float* sigma = (const float*)d_in[5];
    float* out = (float*)d_out;

    char* wsp = (char*)d_ws;
    __hip_bfloat16* xp    = (__hip_bfloat16*)wsp;               // padded x (bf16)
    __hip_bfloat16* avp   = (__hip_bfloat16*)wsp;               // padded av (aliases xp)
    __hip_bfloat16* qkv   = (__hip_bfloat16*)(wsp + QKV_OFF);
    __hip_bfloat16* wqkvp = (__hip_bfloat16*)(wsp + WQKV_OFF);
    __hip_bfloat16* wavp  = (__hip_bfloat16*)(wsp + WAV_OFF);

    // 1. x -> padded channels-last bf16 (halo zeroing fused)
    pack_x_kernel<<<dim3(V_, B_), dim3(256), 0, stream>>>(x, xp);
    // 2. pack weights (pre-swizzled rows)
    pack_w_kernel<<<dim3(32), dim3(256), 0, stream>>>(Wq, Wk, Wv, Wav, wqkvp, wavp);
    // 3. qkv conv (counted-vmcnt phases + setprio + transposed epilogue)
    conv_qkv_mfma<<<dim3(V_, B_), dim3(256), 0, stream>>>(xp, wqkvp, qkv);
    // 4. attention (MFMA, swapped-QK, fixed shift, setprio; AVP halo zero fused)
    attn_mfma<<<dim3(B_ * T_), dim3(256), 0, stream>>>(qkv, avp);
    // 5. output conv (counted-vmcnt phases + setprio + transposed epilogue) + residual
    conv_out_mfma<<<dim3(V_, B_), dim3(256), 0, stream>>>(x, avp, wavp, sigma, out);
}